// Round 1
// baseline (457.772 us; speedup 1.0000x reference)
//
#include <hip/hip_runtime.h>
#include <hip/hip_bf16.h>
#include <math.h>

// MHA forward: B=4, T=2048, D=1024, H=16, HD=64
// Pipeline: cvt weights -> Q/K/V proj GEMMs (bf16 MFMA) -> flash attn -> out proj.

typedef short bf16x8 __attribute__((ext_vector_type(8)));
typedef short bf16x4 __attribute__((ext_vector_type(4)));
typedef float f32x4  __attribute__((ext_vector_type(4)));

#define DEV __device__ __forceinline__

DEV short f2bf(float f) {                 // fp32 -> bf16 RNE
    union { float f; unsigned u; } x; x.f = f;
    unsigned r = x.u + 0x7fffu + ((x.u >> 16) & 1u);
    return (short)(r >> 16);
}

DEV void gload16(const void* g, void* lds_wave_base) {
    __builtin_amdgcn_global_load_lds(
        (const __attribute__((address_space(1))) void*)g,
        (__attribute__((address_space(3))) void*)lds_wave_base, 16, 0, 0);
}

DEV f32x4 mfma16(bf16x8 a, bf16x8 b, f32x4 c) {
    return __builtin_amdgcn_mfma_f32_16x16x32_bf16(a, b, c, 0, 0, 0);
}

// ---------------- weight convert: 1024x1024 fp32 -> bf16 -------------------
__global__ __launch_bounds__(256) void cvt_w(const float* __restrict__ in,
                                             short* __restrict__ out) {
    int i = (blockIdx.x * 256 + threadIdx.x) * 8;   // grid 512 -> exactly 2^20
    f32x4 a = *(const f32x4*)(in + i);
    f32x4 b = *(const f32x4*)(in + i + 4);
    bf16x8 v;
    v[0]=f2bf(a[0]); v[1]=f2bf(a[1]); v[2]=f2bf(a[2]); v[3]=f2bf(a[3]);
    v[4]=f2bf(b[0]); v[5]=f2bf(b[1]); v[6]=f2bf(b[2]); v[7]=f2bf(b[3]);
    *(bf16x8*)(out + i) = v;
}

// ---------------- NT GEMM: C(8192x1024) = A(8192x1024) @ W(1024x1024)^T ----
// EPI: 0 = bf16 store (value+bias)*scale   (Q with scale=0.125, K with 1.0)
//      2 = bf16 store transposed to (B,H,HD,T)   (V)
//      3 = fp32 store + bias                     (final output)
// AF32: A operand is fp32 (reg-stage + convert) vs bf16 (global_load_lds).
// LDS slab layout: [kb 0..3][row 0..127][8 bf16] -> conflict-free b128 frags.
template<int EPI, bool AF32>
__global__ __launch_bounds__(256) void gemm_nt(
    const void* __restrict__ Ap, const short* __restrict__ W,
    const float* __restrict__ bias, void* __restrict__ Cp, float epiScale)
{
    __shared__ short Alds[4096];   // 8 KB
    __shared__ short Blds[4096];   // 8 KB

    const int t    = threadIdx.x;
    const int wave = t >> 6, lane = t & 63;
    const int lr   = lane & 15, lg = lane >> 4;
    const int bid  = blockIdx.x;
    const int m0   = (bid >> 3) * 128, n0 = (bid & 7) * 128;
    const int wr   = wave >> 1, wc = wave & 1;    // 2x2 waves -> 64x64 each

    f32x4 acc[4][4] = {};

    for (int k0 = 0; k0 < 1024; k0 += 32) {
        __syncthreads();
        if constexpr (AF32) {
            const float* A = (const float*)Ap;
            #pragma unroll
            for (int i = 0; i < 2; i++) {
                const int kb  = i * 2 + (t >> 7);
                const int row = t & 127;
                const float* src = A + (size_t)(m0 + row) * 1024 + k0 + kb * 8;
                f32x4 x0 = *(const f32x4*)src;
                f32x4 x1 = *(const f32x4*)(src + 4);
                bf16x8 v;
                v[0]=f2bf(x0[0]); v[1]=f2bf(x0[1]); v[2]=f2bf(x0[2]); v[3]=f2bf(x0[3]);
                v[4]=f2bf(x1[0]); v[5]=f2bf(x1[1]); v[6]=f2bf(x1[2]); v[7]=f2bf(x1[3]);
                *(bf16x8*)(Alds + kb * 1024 + row * 8) = v;
            }
        } else {
            const short* A = (const short*)Ap;
            #pragma unroll
            for (int i = 0; i < 2; i++) {
                const int o = i * 4096 + t * 16;              // byte offset
                const int kb = o >> 11, row = (o >> 4) & 127;
                const short* src = A + (size_t)(m0 + row) * 1024 + k0 + kb * 8;
                gload16(src, (char*)Alds + i * 4096 + wave * 1024);
            }
        }
        #pragma unroll
        for (int i = 0; i < 2; i++) {
            const int o = i * 4096 + t * 16;
            const int kb = o >> 11, row = (o >> 4) & 127;
            const short* src = W + (size_t)(n0 + row) * 1024 + k0 + kb * 8;
            gload16(src, (char*)Blds + i * 4096 + wave * 1024);
        }
        __syncthreads();

        bf16x8 af[4], bfr[4];
        #pragma unroll
        for (int mi = 0; mi < 4; mi++)
            af[mi] = *(const bf16x8*)(Alds + lg * 1024 + (wr * 64 + mi * 16 + lr) * 8);
        #pragma unroll
        for (int ni = 0; ni < 4; ni++)
            bfr[ni] = *(const bf16x8*)(Blds + lg * 1024 + (wc * 64 + ni * 16 + lr) * 8);
        #pragma unroll
        for (int mi = 0; mi < 4; mi++)
            #pragma unroll
            for (int ni = 0; ni < 4; ni++)
                acc[mi][ni] = mfma16(af[mi], bfr[ni], acc[mi][ni]);
    }

    // epilogue: m = m0+wr*64+mi*16+lg*4+r, n = n0+wc*64+ni*16+lr
    #pragma unroll
    for (int mi = 0; mi < 4; mi++) {
        #pragma unroll
        for (int ni = 0; ni < 4; ni++) {
            const int n      = n0 + wc * 64 + ni * 16 + lr;
            const int m_base = m0 + wr * 64 + mi * 16 + lg * 4;
            const float bv   = bias[n];
            f32x4 a = acc[mi][ni];
            if constexpr (EPI == 0) {
                short* C = (short*)Cp;
                #pragma unroll
                for (int r = 0; r < 4; r++)
                    C[(size_t)(m_base + r) * 1024 + n] = f2bf((a[r] + bv) * epiScale);
            } else if constexpr (EPI == 2) {      // V -> (B,H,HD,T)
                short* C = (short*)Cp;
                const int b = m_base >> 11, tt = m_base & 2047;
                bf16x4 p;
                #pragma unroll
                for (int r = 0; r < 4; r++) p[r] = f2bf(a[r] + bv);
                *(bf16x4*)(C + (size_t)b * 2097152 + (size_t)n * 2048 + tt) = p;
            } else {                              // fp32 + bias
                float* C = (float*)Cp;
                #pragma unroll
                for (int r = 0; r < 4; r++)
                    C[(size_t)(m_base + r) * 1024 + n] = a[r] + bv;
            }
        }
    }
}

// ---------------- flash attention ------------------------------------------
// block = (b, h, q-tile of 64). 4 waves, each owns 16 q rows.
// K tile [64 kv][64 hd] and V^T tile [64 hd][64 kv] in LDS, rows padded to 72
// elems (144 B) to break bank conflicts. P re-layout via per-wave LDS buffer.
__global__ __launch_bounds__(256) void attn_fwd(
    const short* __restrict__ Q, const short* __restrict__ K,
    const short* __restrict__ Vt, const unsigned char* __restrict__ mask,
    short* __restrict__ O)
{
    __shared__ short Klds[64 * 72];
    __shared__ short Vlds[64 * 72];
    __shared__ short Plds[4][16 * 72];
    __shared__ unsigned char Mlds[4][1024];

    const int bid = blockIdx.x;
    const int qt  = bid & 31, bh = bid >> 5;
    const int h   = bh & 15,  b  = bh >> 4;
    const int t    = threadIdx.x, wave = t >> 6, lane = t & 63;
    const int lr   = lane & 15,   lg   = lane >> 4;
    const int q0   = qt * 64 + wave * 16;

    bf16x8 qf0, qf1;   // Q already scaled by 1/sqrt(HD)
    {
        const size_t rowQ = ((size_t)b * 2048 + q0 + lr) * 1024 + h * 64;
        qf0 = *(const bf16x8*)(Q + rowQ + lg * 8);
        qf1 = *(const bf16x8*)(Q + rowQ + 32 + lg * 8);
    }

    f32x4 acc[4] = {};                      // out[q=lg*4+r][hd=c*16+lr]
    float mrow[4] = {-INFINITY, -INFINITY, -INFINITY, -INFINITY};
    float lsum[4] = {0.f, 0.f, 0.f, 0.f};

    const int skv  = t >> 2;                // staging row 0..63
    const int segE = (t & 3) * 16;          // staging col base (16 elems = 32B)
    const size_t kbase = ((size_t)b * 2048) * 1024 + h * 64 + segE;
    const size_t vbase = (size_t)b * 2097152 + ((size_t)h * 64 + skv) * 2048 + segE;

    for (int j = 0; j < 32; j++) {
        const int tk0 = j * 64;
        __syncthreads();
        {   // stage K tile (row-major) and V^T tile
            const short* ks = K + kbase + (size_t)(tk0 + skv) * 1024;
            bf16x8 ka = *(const bf16x8*)ks;
            bf16x8 kb2 = *(const bf16x8*)(ks + 8);
            *(bf16x8*)(Klds + skv * 72 + segE)     = ka;
            *(bf16x8*)(Klds + skv * 72 + segE + 8) = kb2;
            const short* vs = Vt + vbase + tk0;
            bf16x8 va = *(const bf16x8*)vs;
            bf16x8 vb2 = *(const bf16x8*)(vs + 8);
            *(bf16x8*)(Vlds + skv * 72 + segE)     = va;
            *(bf16x8*)(Vlds + skv * 72 + segE + 8) = vb2;
        }
        // mask fast-path probe: each lane reads 16 mask bytes of its wave's rows
        uint4 mk = *(const uint4*)(mask + ((size_t)b * 2048 + q0 + (lane >> 2)) * 2048
                                        + tk0 + (lane & 3) * 16);
        const int anym = (mk.x | mk.y | mk.z | mk.w) != 0;
        __syncthreads();

        // S = Q K^T  (S[ni]: q=lg*4+r, kv=ni*16+lr)
        f32x4 S[4] = {};
        #pragma unroll
        for (int ni = 0; ni < 4; ni++) {
            bf16x8 k0f = *(const bf16x8*)(Klds + (ni * 16 + lr) * 72 + lg * 8);
            bf16x8 k1f = *(const bf16x8*)(Klds + (ni * 16 + lr) * 72 + 32 + lg * 8);
            S[ni] = mfma16(qf0, k0f, S[ni]);
            S[ni] = mfma16(qf1, k1f, S[ni]);
        }

        if (__any(anym)) {   // rare slow path (mask all-False in this input)
            *(uint4*)(&Mlds[wave][(lane >> 2) * 64 + (lane & 3) * 16]) = mk;
            asm volatile("s_waitcnt lgkmcnt(0)" ::: "memory");
            __builtin_amdgcn_sched_barrier(0);
            #pragma unroll
            for (int ni = 0; ni < 4; ni++)
                #pragma unroll
                for (int r = 0; r < 4; r++)
                    if (Mlds[wave][(lg * 4 + r) * 64 + ni * 16 + lr])
                        S[ni][r] = -INFINITY;
        }

        // online softmax (wave-parallel, 16-lane-group reductions)
        #pragma unroll
        for (int r = 0; r < 4; r++) {
            float tm = fmaxf(fmaxf(S[0][r], S[1][r]), fmaxf(S[2][r], S[3][r]));
            #pragma unroll
            for (int msk = 1; msk < 16; msk <<= 1)
                tm = fmaxf(tm, __shfl_xor(tm, msk));
            const float mnew = fmaxf(mrow[r], tm);
            const float fs   = exp2f((mrow[r] - mnew) * 1.44269504f);
            mrow[r] = mnew;
            float ps = 0.f;
            #pragma unroll
            for (int ni = 0; ni < 4; ni++) {
                float p = exp2f((S[ni][r] - mnew) * 1.44269504f);
                S[ni][r] = p;
                ps += p;
            }
            #pragma unroll
            for (int msk = 1; msk < 16; msk <<= 1)
                ps += __shfl_xor(ps, msk);
            lsum[r] = lsum[r] * fs + ps;
            #pragma unroll
            for (int c = 0; c < 4; c++) acc[c][r] *= fs;
        }

        // P -> per-wave LDS (bf16), then re-read in A-fragment layout
        #pragma unroll
        for (int ni = 0; ni < 4; ni++)
            #pragma unroll
            for (int r = 0; r < 4; r++)
                Plds[wave][(lg * 4 + r) * 72 + ni * 16 + lr] = f2bf(S[ni][r]);
        asm volatile("s_waitcnt lgkmcnt(0)" ::: "memory");
        __builtin_amdgcn_sched_barrier(0);

        // acc += P @ V  (B-frag from V^T rows, contiguous)
        #pragma unroll
        for (int kc = 0; kc < 2; kc++) {
            bf16x8 pf = *(const bf16x8*)(&Plds[wave][lr * 72 + kc * 32 + lg * 8]);
            #pragma unroll
            for (int c = 0; c < 4; c++) {
                bf16x8 vf = *(const bf16x8*)(Vlds + (c * 16 + lr) * 72 + kc * 32 + lg * 8);
                acc[c] = mfma16(pf, vf, acc[c]);
            }
        }
    }

    #pragma unroll
    for (int r = 0; r < 4; r++) {
        const float inv = 1.0f / lsum[r];
        const size_t orow = ((size_t)b * 2048 + q0 + lg * 4 + r) * 1024 + h * 64;
        #pragma unroll
        for (int c = 0; c < 4; c++)
            O[orow + c * 16 + lr] = f2bf(acc[c][r] * inv);
    }
}

// ---------------- launch ----------------------------------------------------
extern "C" void kernel_launch(void* const* d_in, const int* in_sizes, int n_in,
                              void* d_out, int out_size, void* d_ws, size_t ws_size,
                              hipStream_t stream)
{
    const float* query = (const float*)d_in[0];
    const float* key_  = (const float*)d_in[1];
    const float* value = (const float*)d_in[2];
    const unsigned char* amask = (const unsigned char*)d_in[3];
    const float* Wq = (const float*)d_in[4];
    const float* bq = (const float*)d_in[5];
    const float* Wk = (const float*)d_in[6];
    const float* bk = (const float*)d_in[7];
    const float* Wv = (const float*)d_in[8];
    const float* bv = (const float*)d_in[9];
    const float* Wo = (const float*)d_in[10];
    const float* bo = (const float*)d_in[11];
    float* out = (float*)d_out;

    char* ws = (char*)d_ws;
    const size_t MB = 1024 * 1024;
    short* Wqb = (short*)(ws + 0 * MB);    // 2 MB each
    short* Wkb = (short*)(ws + 2 * MB);
    short* Wvb = (short*)(ws + 4 * MB);
    short* Wob = (short*)(ws + 6 * MB);
    short* Qb  = (short*)(ws + 8 * MB);    // 16 MB each
    short* Kb  = (short*)(ws + 24 * MB);
    short* Vtb = (short*)(ws + 40 * MB);
    short* AOb = (short*)(ws + 56 * MB);   // total 72 MB

    cvt_w<<<512, 256, 0, stream>>>(Wq, Wqb);
    cvt_w<<<512, 256, 0, stream>>>(Wk, Wkb);
    cvt_w<<<512, 256, 0, stream>>>(Wv, Wvb);
    cvt_w<<<512, 256, 0, stream>>>(Wo, Wob);

    gemm_nt<0, true ><<<512, 256, 0, stream>>>(query, Wqb, bq, Qb,  0.125f);
    gemm_nt<0, true ><<<512, 256, 0, stream>>>(key_,  Wkb, bk, Kb,  1.0f);
    gemm_nt<2, true ><<<512, 256, 0, stream>>>(value, Wvb, bv, Vtb, 1.0f);

    attn_fwd<<<2048, 256, 0, stream>>>(Qb, Kb, Vtb, amask, AOb);

    gemm_nt<3, false><<<512, 256, 0, stream>>>(AOb, Wob, bo, out, 1.0f);
}

// Round 2
// 336.308 us; speedup vs baseline: 1.3612x; 1.3612x over previous
//
#include <hip/hip_runtime.h>
#include <hip/hip_bf16.h>
#include <math.h>

// MHA forward: B=4, T=2048, D=1024, H=16, HD=64
// cvt weights -> Q/K/V proj GEMMs -> mask scan -> flash attn (32x32 swapped) -> out proj.

typedef short bf16x8 __attribute__((ext_vector_type(8)));
typedef short bf16x4 __attribute__((ext_vector_type(4)));
typedef float f32x4  __attribute__((ext_vector_type(4)));
typedef float f32x16 __attribute__((ext_vector_type(16)));
typedef unsigned u32x4v __attribute__((ext_vector_type(4)));

#define DEV __device__ __forceinline__

DEV short f2bf(float f) {                 // fp32 -> bf16 RNE
    union { float f; unsigned u; } x; x.f = f;
    unsigned r = x.u + 0x7fffu + ((x.u >> 16) & 1u);
    return (short)(r >> 16);
}

DEV unsigned cvtpk(float lo, float hi) {  // pack 2 f32 -> 2 bf16 (RNE)
    unsigned r;
    asm("v_cvt_pk_bf16_f32 %0, %1, %2" : "=v"(r) : "v"(lo), "v"(hi));
    return r;
}

DEV void pl32swap(unsigned &a, unsigned &b) {  // a'={a.lo,b.lo}, b'={a.hi,b.hi}
    asm volatile("v_permlane32_swap_b32 %0, %1" : "+v"(a), "+v"(b));
}

DEV void gload16(const void* g, void* lds_wave_base) {
    __builtin_amdgcn_global_load_lds(
        (const __attribute__((address_space(1))) void*)g,
        (__attribute__((address_space(3))) void*)lds_wave_base, 16, 0, 0);
}

DEV f32x4 mfma16(bf16x8 a, bf16x8 b, f32x4 c) {
    return __builtin_amdgcn_mfma_f32_16x16x32_bf16(a, b, c, 0, 0, 0);
}
DEV f32x16 mfma32(bf16x8 a, bf16x8 b, f32x16 c) {
    return __builtin_amdgcn_mfma_f32_32x32x16_bf16(a, b, c, 0, 0, 0);
}

// ---------------- weight convert: 1024x1024 fp32 -> bf16 -------------------
__global__ __launch_bounds__(256) void cvt_w(const float* __restrict__ in,
                                             short* __restrict__ out) {
    int i = (blockIdx.x * 256 + threadIdx.x) * 8;
    f32x4 a = *(const f32x4*)(in + i);
    f32x4 b = *(const f32x4*)(in + i + 4);
    bf16x8 v;
    v[0]=f2bf(a[0]); v[1]=f2bf(a[1]); v[2]=f2bf(a[2]); v[3]=f2bf(a[3]);
    v[4]=f2bf(b[0]); v[5]=f2bf(b[1]); v[6]=f2bf(b[2]); v[7]=f2bf(b[3]);
    *(bf16x8*)(out + i) = v;
}

// ---------------- NT GEMM: C(8192x1024) = A(8192x1024) @ W(1024x1024)^T ----
template<int EPI, bool AF32>
__global__ __launch_bounds__(256) void gemm_nt(
    const void* __restrict__ Ap, const short* __restrict__ W,
    const float* __restrict__ bias, void* __restrict__ Cp, float epiScale)
{
    __shared__ short Alds[4096];
    __shared__ short Blds[4096];

    const int t    = threadIdx.x;
    const int wave = t >> 6, lane = t & 63;
    const int lr   = lane & 15, lg = lane >> 4;
    const int bid  = blockIdx.x;
    const int m0   = (bid >> 3) * 128, n0 = (bid & 7) * 128;
    const int wr   = wave >> 1, wc = wave & 1;

    f32x4 acc[4][4] = {};

    for (int k0 = 0; k0 < 1024; k0 += 32) {
        __syncthreads();
        if constexpr (AF32) {
            const float* A = (const float*)Ap;
            #pragma unroll
            for (int i = 0; i < 2; i++) {
                const int kb  = i * 2 + (t >> 7);
                const int row = t & 127;
                const float* src = A + (size_t)(m0 + row) * 1024 + k0 + kb * 8;
                f32x4 x0 = *(const f32x4*)src;
                f32x4 x1 = *(const f32x4*)(src + 4);
                bf16x8 v;
                v[0]=f2bf(x0[0]); v[1]=f2bf(x0[1]); v[2]=f2bf(x0[2]); v[3]=f2bf(x0[3]);
                v[4]=f2bf(x1[0]); v[5]=f2bf(x1[1]); v[6]=f2bf(x1[2]); v[7]=f2bf(x1[3]);
                *(bf16x8*)(Alds + kb * 1024 + row * 8) = v;
            }
        } else {
            const short* A = (const short*)Ap;
            #pragma unroll
            for (int i = 0; i < 2; i++) {
                const int o = i * 4096 + t * 16;
                const int kb = o >> 11, row = (o >> 4) & 127;
                const short* src = A + (size_t)(m0 + row) * 1024 + k0 + kb * 8;
                gload16(src, (char*)Alds + i * 4096 + wave * 1024);
            }
        }
        #pragma unroll
        for (int i = 0; i < 2; i++) {
            const int o = i * 4096 + t * 16;
            const int kb = o >> 11, row = (o >> 4) & 127;
            const short* src = W + (size_t)(n0 + row) * 1024 + k0 + kb * 8;
            gload16(src, (char*)Blds + i * 4096 + wave * 1024);
        }
        __syncthreads();

        bf16x8 af[4], bfr[4];
        #pragma unroll
        for (int mi = 0; mi < 4; mi++)
            af[mi] = *(const bf16x8*)(Alds + lg * 1024 + (wr * 64 + mi * 16 + lr) * 8);
        #pragma unroll
        for (int ni = 0; ni < 4; ni++)
            bfr[ni] = *(const bf16x8*)(Blds + lg * 1024 + (wc * 64 + ni * 16 + lr) * 8);
        #pragma unroll
        for (int mi = 0; mi < 4; mi++)
            #pragma unroll
            for (int ni = 0; ni < 4; ni++)
                acc[mi][ni] = mfma16(af[mi], bfr[ni], acc[mi][ni]);
    }

    #pragma unroll
    for (int mi = 0; mi < 4; mi++) {
        #pragma unroll
        for (int ni = 0; ni < 4; ni++) {
            const int n      = n0 + wc * 64 + ni * 16 + lr;
            const int m_base = m0 + wr * 64 + mi * 16 + lg * 4;
            const float bv   = bias[n];
            f32x4 a = acc[mi][ni];
            if constexpr (EPI == 0) {
                short* C = (short*)Cp;
                #pragma unroll
                for (int r = 0; r < 4; r++)
                    C[(size_t)(m_base + r) * 1024 + n] = f2bf((a[r] + bv) * epiScale);
            } else if constexpr (EPI == 2) {      // V -> (B,H,HD,T)
                short* C = (short*)Cp;
                const int b = m_base >> 11, tt = m_base & 2047;
                bf16x4 p;
                #pragma unroll
                for (int r = 0; r < 4; r++) p[r] = f2bf(a[r] + bv);
                *(bf16x4*)(C + (size_t)b * 2097152 + (size_t)n * 2048 + tt) = p;
            } else {
                float* C = (float*)Cp;
                #pragma unroll
                for (int r = 0; r < 4; r++)
                    C[(size_t)(m_base + r) * 1024 + n] = a[r] + bv;
            }
        }
    }
}

// ---------------- mask pre-scan: flags[b][qt32][kt64] = any(mask tile) -----
__global__ __launch_bounds__(256) void mask_scan(const unsigned char* __restrict__ mask,
                                                 unsigned char* __restrict__ flags) {
    __shared__ int anyk[32];
    const int t = threadIdx.x, kt = t & 31, g = t >> 5;
    const int b = blockIdx.x >> 6, qt = blockIdx.x & 63;
    if (t < 32) anyk[t] = 0;
    __syncthreads();
    unsigned acc = 0;
    const unsigned char* base = mask + ((size_t)b * 2048 + qt * 32 + g * 4) * 2048 + kt * 64;
    #pragma unroll
    for (int rr = 0; rr < 4; rr++) {
        const uint4* p = (const uint4*)(base + (size_t)rr * 2048);
        #pragma unroll
        for (int s = 0; s < 4; s++) { uint4 v = p[s]; acc |= v.x | v.y | v.z | v.w; }
    }
    if (acc) anyk[kt] = 1;
    __syncthreads();
    if (t < 32) flags[((size_t)b * 64 + qt) * 32 + t] = (unsigned char)anyk[t];
}

// ---------------- flash attention, swapped QK^T on 32x32x16 ----------------
// 4 warps x 32 q rows = 128 q per block; KV tile 64, double-buffered LDS,
// XOR-swizzled via pre-swizzled global_load_lds source. S^T in registers:
// lane q = lane&31, kv = (r&3)+8*(r>>2)+4*(lane>>5) (+32 for second acc).
__global__ __launch_bounds__(256, 2) void attn_fwd2(
    const short* __restrict__ Q, const short* __restrict__ K,
    const short* __restrict__ Vt, const unsigned char* __restrict__ mask,
    const unsigned char* __restrict__ flags, short* __restrict__ O)
{
    __shared__ short lds[2][2][4096];   // [buf][K=0/V=1][64 rows x 64]

    const int t = threadIdx.x, wave = t >> 6, lane = t & 63;
    const int j31 = lane & 31, hi = lane >> 5;

    const int raw = blockIdx.x;
    const int wg  = (raw & 7) * 128 + (raw >> 3);      // XCD-chunked swizzle
    const int qblk = wg & 15, bh = wg >> 4;
    const int h = bh & 15, b = bh >> 4;
    const int q0 = qblk * 128 + wave * 32;

    // Q B-fragments (q pre-scaled by 0.125*log2e in GEMM epilogue)
    bf16x8 qf[4];
    {
        const short* qp = Q + ((size_t)b * 2048 + q0 + j31) * 1024 + h * 64 + hi * 8;
        #pragma unroll
        for (int ck = 0; ck < 4; ck++) qf[ck] = *(const bf16x8*)(qp + ck * 16);
    }
    // per-warp tile flags -> 32-bit uniform mask via ballot
    unsigned long long fmask;
    {
        unsigned char fb = flags[((size_t)b * 64 + qblk * 4 + wave) * 32 + j31];
        fmask = __ballot(fb != 0);
    }

    const short* Kg = K + ((size_t)b * 2048) * 1024 + h * 64;
    const short* Vg = Vt + (size_t)b * 2097152 + (size_t)h * 64 * 2048;

    // prologue: stage tile 0 into buf 0 (pre-swizzled source, linear LDS dest)
    #pragma unroll
    for (int i = 0; i < 2; i++) {
        const int slot = i * 256 + t, row = slot >> 3;
        const int cs = ((slot & 7) ^ (row & 7)) * 8;
        gload16(Kg + (size_t)row * 1024 + cs, &lds[0][0][i * 2048 + wave * 512]);
        gload16(Vg + (size_t)row * 2048 + cs, &lds[0][1][i * 2048 + wave * 512]);
    }

    f32x16 oA = {}, oB = {};
    float m = -1e30f, l = 0.f;
    int buf = 0;

    for (int j = 0; j < 32; ++j) {
        if (j < 31) {   // stage next tile into buf^1 (safe: barrier'd last iter)
            const int tk = (j + 1) * 64;
            #pragma unroll
            for (int i = 0; i < 2; i++) {
                const int slot = i * 256 + t, row = slot >> 3;
                const int cs = ((slot & 7) ^ (row & 7)) * 8;
                gload16(Kg + (size_t)(tk + row) * 1024 + cs,
                        &lds[buf ^ 1][0][i * 2048 + wave * 512]);
                gload16(Vg + (size_t)row * 2048 + tk + cs,
                        &lds[buf ^ 1][1][i * 2048 + wave * 512]);
            }
            asm volatile("s_waitcnt vmcnt(4)" ::: "memory");   // current buf ready
        } else {
            asm volatile("s_waitcnt vmcnt(0)" ::: "memory");
        }
        __builtin_amdgcn_s_barrier();

        const short* ldsK = &lds[buf][0][0];
        const short* ldsV = &lds[buf][1][0];
        const int sw = j31 & 7;                     // row-XOR key (rows r and r+32 share it)

        // S^T = K Q^T : two 32-kv halves
        f32x16 sA = {}, sB = {};
        __builtin_amdgcn_s_setprio(1);
        #pragma unroll
        for (int ck = 0; ck < 4; ck++) {
            bf16x8 kf0 = *(const bf16x8*)(ldsK + j31 * 64        + (((2*ck + hi) ^ sw) * 8));
            bf16x8 kf1 = *(const bf16x8*)(ldsK + (32 + j31) * 64 + (((2*ck + hi) ^ sw) * 8));
            sA = mfma32(kf0, qf[ck], sA);
            sB = mfma32(kf1, qf[ck], sB);
        }
        __builtin_amdgcn_s_setprio(0);

        if ((fmask >> j) & 1ULL) {   // rare mask slow path
            const unsigned char* mp = mask + ((size_t)b * 2048 + q0 + j31) * 2048
                                           + (size_t)j * 64 + hi * 4;
            #pragma unroll
            for (int a = 0; a < 2; a++)
                #pragma unroll
                for (int rg = 0; rg < 4; rg++) {
                    unsigned mb = *(const unsigned*)(mp + a * 32 + rg * 8);
                    #pragma unroll
                    for (int e = 0; e < 4; e++) {
                        if ((mb >> (8 * e)) & 0xFFu) {
                            if (a == 0) sA[rg * 4 + e] = -1e30f;
                            else        sB[rg * 4 + e] = -1e30f;
                        }
                    }
                }
        }

        // online softmax: in-lane over 32 regs + one cross-half exchange
        float tm = sA[0];
        #pragma unroll
        for (int r = 1; r < 16; r++) tm = fmaxf(tm, sA[r]);
        #pragma unroll
        for (int r = 0; r < 16; r++) tm = fmaxf(tm, sB[r]);
        tm = fmaxf(tm, __shfl_xor(tm, 32));
        if (!__all(tm <= m + 8.f)) {        // defer-max (T13), log2 domain
            const float mnew = fmaxf(m, tm);
            const float fs = exp2f(m - mnew);
            m = mnew; l *= fs;
            #pragma unroll
            for (int r = 0; r < 16; r++) { oA[r] *= fs; oB[r] *= fs; }
        }
        float ps = 0.f;
        #pragma unroll
        for (int r = 0; r < 16; r++) { sA[r] = exp2f(sA[r] - m); ps += sA[r]; }
        #pragma unroll
        for (int r = 0; r < 16; r++) { sB[r] = exp2f(sB[r] - m); ps += sB[r]; }
        ps += __shfl_xor(ps, 32);
        l += ps;

        // P -> PV B-fragments: 16 cvt_pk + 8 permlane32_swap (T12)
        bf16x8 pb[4];
        #pragma unroll
        for (int c = 0; c < 4; c++) {
            const int rb = 8 * (c & 1);
            unsigned A0, B0, A1, B1;
            if (c < 2) {
                A0 = cvtpk(sA[rb],     sA[rb + 1]); B0 = cvtpk(sA[rb + 4], sA[rb + 5]);
                A1 = cvtpk(sA[rb + 2], sA[rb + 3]); B1 = cvtpk(sA[rb + 6], sA[rb + 7]);
            } else {
                A0 = cvtpk(sB[rb],     sB[rb + 1]); B0 = cvtpk(sB[rb + 4], sB[rb + 5]);
                A1 = cvtpk(sB[rb + 2], sB[rb + 3]); B1 = cvtpk(sB[rb + 6], sB[rb + 7]);
            }
            pl32swap(A0, B0); pl32swap(A1, B1);
            union { unsigned u[4]; bf16x8 v; } pu;
            pu.u[0] = A0; pu.u[1] = A1; pu.u[2] = B0; pu.u[3] = B1;
            pb[c] = pu.v;
        }

        // O^T += V^T P^T
        __builtin_amdgcn_s_setprio(1);
        #pragma unroll
        for (int c = 0; c < 4; c++) {
            bf16x8 vf0 = *(const bf16x8*)(ldsV + j31 * 64        + (((2*c + hi) ^ sw) * 8));
            bf16x8 vf1 = *(const bf16x8*)(ldsV + (32 + j31) * 64 + (((2*c + hi) ^ sw) * 8));
            oA = mfma32(vf0, pb[c], oA);
            oB = mfma32(vf1, pb[c], oB);
        }
        __builtin_amdgcn_s_setprio(0);
        __builtin_amdgcn_s_barrier();
        buf ^= 1;
    }

    // epilogue: transpose O^T -> O rows via LDS (per-warp region, stride 34 u32)
    __syncthreads();
    unsigned* ow = (unsigned*)&lds[0][0][0] + wave * (32 * 34);
    const float inv = 1.f / l;
    #pragma unroll
    for (int o = 0; o < 2; o++)
        #pragma unroll
        for (int rp = 0; rp < 8; rp++) {
            const int r  = 2 * rp;
            const int hd = 2 * (rp & 1) + 8 * (rp >> 1) + 4 * hi + 32 * o;
            const float v0 = (o ? oB[r]     : oA[r])     * inv;
            const float v1 = (o ? oB[r + 1] : oA[r + 1]) * inv;
            ow[j31 * 34 + (hd >> 1)] = cvtpk(v0, v1);
        }
    __syncthreads();
    {
        const size_t orow = ((size_t)b * 2048 + q0 + j31) * 1024 + h * 64 + hi * 32;
        unsigned* gout = (unsigned*)(O + orow);
        const unsigned* src = ow + j31 * 34 + hi * 16;
        #pragma unroll
        for (int i = 0; i < 4; i++) {
            u32x4v v;
            v[0] = src[i*4]; v[1] = src[i*4+1]; v[2] = src[i*4+2]; v[3] = src[i*4+3];
            *(u32x4v*)(gout + i * 4) = v;
        }
    }
}

// ---------------- launch ----------------------------------------------------
extern "C" void kernel_launch(void* const* d_in, const int* in_sizes, int n_in,
                              void* d_out, int out_size, void* d_ws, size_t ws_size,
                              hipStream_t stream)
{
    const float* query = (const float*)d_in[0];
    const float* key_  = (const float*)d_in[1];
    const float* value = (const float*)d_in[2];
    const unsigned char* amask = (const unsigned char*)d_in[3];
    const float* Wq = (const float*)d_in[4];
    const float* bq = (const float*)d_in[5];
    const float* Wk = (const float*)d_in[6];
    const float* bk = (const float*)d_in[7];
    const float* Wv = (const float*)d_in[8];
    const float* bv = (const float*)d_in[9];
    const float* Wo = (const float*)d_in[10];
    const float* bo = (const float*)d_in[11];
    float* out = (float*)d_out;

    char* ws = (char*)d_ws;
    const size_t MB = 1024 * 1024;
    short* Wqb = (short*)(ws + 0 * MB);
    short* Wkb = (short*)(ws + 2 * MB);
    short* Wvb = (short*)(ws + 4 * MB);
    short* Wob = (short*)(ws + 6 * MB);
    short* Qb  = (short*)(ws + 8 * MB);
    short* Kb  = (short*)(ws + 24 * MB);
    short* Vtb = (short*)(ws + 40 * MB);
    short* AOb = (short*)(ws + 56 * MB);
    unsigned char* flagsb = (unsigned char*)(ws + 0 * MB);  // reuse Wqb region (dead after Q GEMM)

    cvt_w<<<512, 256, 0, stream>>>(Wq, Wqb);
    cvt_w<<<512, 256, 0, stream>>>(Wk, Wkb);
    cvt_w<<<512, 256, 0, stream>>>(Wv, Wvb);
    cvt_w<<<512, 256, 0, stream>>>(Wo, Wob);

    const float qscale = 0.125f * 1.44269504088896f;   // 1/sqrt(64) * log2(e)
    gemm_nt<0, true ><<<512, 256, 0, stream>>>(query, Wqb, bq, Qb,  qscale);
    gemm_nt<0, true ><<<512, 256, 0, stream>>>(key_,  Wkb, bk, Kb,  1.0f);
    gemm_nt<2, true ><<<512, 256, 0, stream>>>(value, Wvb, bv, Vtb, 1.0f);

    mask_scan<<<256, 256, 0, stream>>>(amask, flagsb);

    attn_fwd2<<<1024, 256, 0, stream>>>(Qb, Kb, Vtb, amask, flagsb, AOb);

    gemm_nt<3, false><<<512, 256, 0, stream>>>(AOb, Wob, bo, out, 1.0f);
}

// Round 3
// 286.140 us; speedup vs baseline: 1.5998x; 1.1753x over previous
//
#include <hip/hip_runtime.h>
#include <hip/hip_bf16.h>
#include <math.h>

// MHA forward: B=4, T=2048, D=1024, H=16, HD=64
// cvt(all fp32->bf16) -> Q/K/V proj GEMMs (2-phase dbuf) -> mask scan
//   -> flash attn (32x32 swapped, raw v_exp) -> out proj.

typedef short bf16x8 __attribute__((ext_vector_type(8)));
typedef short bf16x4 __attribute__((ext_vector_type(4)));
typedef float f32x4  __attribute__((ext_vector_type(4)));
typedef float f32x16 __attribute__((ext_vector_type(16)));
typedef unsigned u32x4v __attribute__((ext_vector_type(4)));

#define DEV __device__ __forceinline__

DEV short f2bf(float f) {                 // fp32 -> bf16 RNE
    union { float f; unsigned u; } x; x.f = f;
    unsigned r = x.u + 0x7fffu + ((x.u >> 16) & 1u);
    return (short)(r >> 16);
}

DEV unsigned cvtpk(float lo, float hi) {  // pack 2 f32 -> 2 bf16 (RNE)
    unsigned r;
    asm("v_cvt_pk_bf16_f32 %0, %1, %2" : "=v"(r) : "v"(lo), "v"(hi));
    return r;
}

DEV void pl32swap(unsigned &a, unsigned &b) {
    asm volatile("v_permlane32_swap_b32 %0, %1" : "+v"(a), "+v"(b));
}

DEV float fexp2(float x) {                // raw v_exp_f32 (+1 wait state for TRANS hazard)
    float r;
    asm("v_exp_f32 %0, %1\n\ts_nop 0" : "=v"(r) : "v"(x));
    return r;
}

DEV void gload16(const void* g, void* lds_wave_base) {
    __builtin_amdgcn_global_load_lds(
        (const __attribute__((address_space(1))) void*)g,
        (__attribute__((address_space(3))) void*)lds_wave_base, 16, 0, 0);
}

DEV f32x4 mfma16(bf16x8 a, bf16x8 b, f32x4 c) {
    return __builtin_amdgcn_mfma_f32_16x16x32_bf16(a, b, c, 0, 0, 0);
}
DEV f32x16 mfma32(bf16x8 a, bf16x8 b, f32x16 c) {
    return __builtin_amdgcn_mfma_f32_32x32x16_bf16(a, b, c, 0, 0, 0);
}

// ---------------- fp32 -> bf16 converts ------------------------------------
__global__ __launch_bounds__(256) void cvt_one(const float* __restrict__ in,
                                               short* __restrict__ out) {
    int i = (blockIdx.x * 256 + threadIdx.x) * 8;
    f32x4 a = *(const f32x4*)(in + i);
    f32x4 b = *(const f32x4*)(in + i + 4);
    bf16x8 v;
    v[0]=f2bf(a[0]); v[1]=f2bf(a[1]); v[2]=f2bf(a[2]); v[3]=f2bf(a[3]);
    v[4]=f2bf(b[0]); v[5]=f2bf(b[1]); v[6]=f2bf(b[2]); v[7]=f2bf(b[3]);
    *(bf16x8*)(out + i) = v;
}

__global__ __launch_bounds__(256) void cvt_w4(
    const float* __restrict__ a, const float* __restrict__ b,
    const float* __restrict__ c, const float* __restrict__ d,
    short* __restrict__ oa, short* __restrict__ ob,
    short* __restrict__ oc, short* __restrict__ od) {
    const int sel = blockIdx.x >> 9;
    const float* in = sel == 0 ? a : sel == 1 ? b : sel == 2 ? c : d;
    short* out      = sel == 0 ? oa : sel == 1 ? ob : sel == 2 ? oc : od;
    int i = ((blockIdx.x & 511) * 256 + threadIdx.x) * 8;
    f32x4 x = *(const f32x4*)(in + i);
    f32x4 y = *(const f32x4*)(in + i + 4);
    bf16x8 v;
    v[0]=f2bf(x[0]); v[1]=f2bf(x[1]); v[2]=f2bf(x[2]); v[3]=f2bf(x[3]);
    v[4]=f2bf(y[0]); v[5]=f2bf(y[1]); v[6]=f2bf(y[2]); v[7]=f2bf(y[3]);
    *(bf16x8*)(out + i) = v;
}

// ---------------- NT GEMM, bf16, 2-phase double-buffered -------------------
// C(8192x1024) = A(8192x1024) @ W(1024x1024)^T ; 128x128 tile, BK=32.
// EPI: 0 = bf16 (v+bias)*scale ; 2 = bf16 transposed to (B,H,HD,T) ; 3 = fp32+bias
template<int EPI>
__global__ __launch_bounds__(256) void gemm_bt(
    const short* __restrict__ A, const short* __restrict__ W,
    const float* __restrict__ bias, void* __restrict__ Cp, float epiScale)
{
    __shared__ short Alds[2][4096];
    __shared__ short Blds[2][4096];

    const int t = threadIdx.x;
    const int wave = t >> 6, lane = t & 63;
    const int lr = lane & 15, lg = lane >> 4;
    const int wg = (blockIdx.x & 7) * 64 + (blockIdx.x >> 3);   // XCD swizzle (512%8==0)
    const int m0 = (wg >> 3) * 128, n0 = (wg & 7) * 128;
    const int wr = wave >> 1, wc = wave & 1;

    // per-thread staging sources (slab layout [kb][row][8])
    const int o0 = t * 16,        kb0 = o0 >> 11, row0 = (o0 >> 4) & 127;
    const int o1 = 4096 + t * 16, kb1 = o1 >> 11, row1 = (o1 >> 4) & 127;
    const short* As0 = A + (size_t)(m0 + row0) * 1024 + kb0 * 8;
    const short* As1 = A + (size_t)(m0 + row1) * 1024 + kb1 * 8;
    const short* Ws0 = W + (size_t)(n0 + row0) * 1024 + kb0 * 8;
    const short* Ws1 = W + (size_t)(n0 + row1) * 1024 + kb1 * 8;

    auto stage = [&](short* dA, short* dB, int k0) {
        gload16(As0 + k0, (char*)dA + wave * 1024);
        gload16(As1 + k0, (char*)dA + 4096 + wave * 1024);
        gload16(Ws0 + k0, (char*)dB + wave * 1024);
        gload16(Ws1 + k0, (char*)dB + 4096 + wave * 1024);
    };

    f32x4 acc[4][4] = {};

    stage(Alds[0], Blds[0], 0);

    auto kstep = [&](int ts, int BUF) {
        if (ts < 31) {
            stage(Alds[BUF ^ 1], Blds[BUF ^ 1], (ts + 1) * 32);
            asm volatile("s_waitcnt vmcnt(4)" ::: "memory");
        } else {
            asm volatile("s_waitcnt vmcnt(0)" ::: "memory");
        }
        __builtin_amdgcn_s_barrier();
        bf16x8 af[4], bfr[4];
        #pragma unroll
        for (int mi = 0; mi < 4; mi++)
            af[mi] = *(const bf16x8*)(Alds[BUF] + lg * 1024 + (wr * 64 + mi * 16 + lr) * 8);
        #pragma unroll
        for (int ni = 0; ni < 4; ni++)
            bfr[ni] = *(const bf16x8*)(Blds[BUF] + lg * 1024 + (wc * 64 + ni * 16 + lr) * 8);
        #pragma unroll
        for (int mi = 0; mi < 4; mi++)
            #pragma unroll
            for (int ni = 0; ni < 4; ni++)
                acc[mi][ni] = mfma16(af[mi], bfr[ni], acc[mi][ni]);
        __builtin_amdgcn_s_barrier();
    };

    #pragma unroll 1
    for (int it = 0; it < 16; ++it) { kstep(2 * it, 0); kstep(2 * it + 1, 1); }

    #pragma unroll
    for (int mi = 0; mi < 4; mi++) {
        #pragma unroll
        for (int ni = 0; ni < 4; ni++) {
            const int n      = n0 + wc * 64 + ni * 16 + lr;
            const int m_base = m0 + wr * 64 + mi * 16 + lg * 4;
            const float bv   = bias[n];
            f32x4 a = acc[mi][ni];
            if constexpr (EPI == 0) {
                short* C = (short*)Cp;
                #pragma unroll
                for (int r = 0; r < 4; r++)
                    C[(size_t)(m_base + r) * 1024 + n] = f2bf((a[r] + bv) * epiScale);
            } else if constexpr (EPI == 2) {      // V -> (B,H,HD,T)
                short* C = (short*)Cp;
                const int b = m_base >> 11, tt = m_base & 2047;
                bf16x4 p;
                #pragma unroll
                for (int r = 0; r < 4; r++) p[r] = f2bf(a[r] + bv);
                *(bf16x4*)(C + (size_t)b * 2097152 + (size_t)n * 2048 + tt) = p;
            } else {
                float* C = (float*)Cp;
                #pragma unroll
                for (int r = 0; r < 4; r++)
                    C[(size_t)(m_base + r) * 1024 + n] = a[r] + bv;
            }
        }
    }
}

// ---------------- mask pre-scan: flags[b][qt32][kt64] = any(mask tile) -----
__global__ __launch_bounds__(256) void mask_scan(const unsigned char* __restrict__ mask,
                                                 unsigned char* __restrict__ flags) {
    __shared__ int anyk[32];
    const int t = threadIdx.x, kt = t & 31, g = t >> 5;
    const int b = blockIdx.x >> 6, qt = blockIdx.x & 63;
    if (t < 32) anyk[t] = 0;
    __syncthreads();
    unsigned acc = 0;
    const unsigned char* base = mask + ((size_t)b * 2048 + qt * 32 + g * 4) * 2048 + kt * 64;
    #pragma unroll
    for (int rr = 0; rr < 4; rr++) {
        const uint4* p = (const uint4*)(base + (size_t)rr * 2048);
        #pragma unroll
        for (int s = 0; s < 4; s++) { uint4 v = p[s]; acc |= v.x | v.y | v.z | v.w; }
    }
    if (acc) anyk[kt] = 1;
    __syncthreads();
    if (t < 32) flags[((size_t)b * 64 + qt) * 32 + t] = (unsigned char)anyk[t];
}

// ---------------- flash attention, swapped QK^T on 32x32x16 ----------------
__global__ __launch_bounds__(256, 2) void attn_fwd2(
    const short* __restrict__ Q, const short* __restrict__ K,
    const short* __restrict__ Vt, const unsigned char* __restrict__ mask,
    const unsigned char* __restrict__ flags, short* __restrict__ O)
{
    __shared__ short lds[2][2][4096];   // [buf][K=0/V=1][64 rows x 64]

    const int t = threadIdx.x, wave = t >> 6, lane = t & 63;
    const int j31 = lane & 31, hi = lane >> 5;

    const int raw = blockIdx.x;
    const int wg  = (raw & 7) * 128 + (raw >> 3);      // XCD swizzle (1024%8==0)
    const int qblk = wg & 15, bh = wg >> 4;
    const int h = bh & 15, b = bh >> 4;
    const int q0 = qblk * 128 + wave * 32;

    bf16x8 qf[4];     // Q pre-scaled by 0.125*log2e
    {
        const short* qp = Q + ((size_t)b * 2048 + q0 + j31) * 1024 + h * 64 + hi * 8;
        #pragma unroll
        for (int ck = 0; ck < 4; ck++) qf[ck] = *(const bf16x8*)(qp + ck * 16);
    }
    unsigned long long fmask;
    {
        unsigned char fb = flags[((size_t)b * 64 + qblk * 4 + wave) * 32 + j31];
        fmask = __ballot(fb != 0);
    }

    const short* Kg = K + ((size_t)b * 2048) * 1024 + h * 64;
    const short* Vg = Vt + (size_t)b * 2097152 + (size_t)h * 64 * 2048;

    auto stage = [&](short* dK, short* dV, int tk) {
        #pragma unroll
        for (int i = 0; i < 2; i++) {
            const int slot = i * 256 + t, row = slot >> 3;
            const int cs = ((slot & 7) ^ (row & 7)) * 8;
            gload16(Kg + (size_t)(tk + row) * 1024 + cs, dK + i * 2048 + wave * 512);
            gload16(Vg + (size_t)row * 2048 + tk + cs, dV + i * 2048 + wave * 512);
        }
    };

    stage(&lds[0][0][0], &lds[0][1][0], 0);

    f32x16 oA = {}, oB = {};
    float m = -1e30f, l = 0.f;
    const int sw = j31 & 7;     // rows r and r+32 share the XOR key

    auto tile = [&](int J, int BUF) {
        if (J < 31) {
            stage(&lds[BUF ^ 1][0][0], &lds[BUF ^ 1][1][0], (J + 1) * 64);
            asm volatile("s_waitcnt vmcnt(4)" ::: "memory");
        } else {
            asm volatile("s_waitcnt vmcnt(0)" ::: "memory");
        }
        __builtin_amdgcn_s_barrier();
        const short* ldsK = &lds[BUF][0][0];
        const short* ldsV = &lds[BUF][1][0];

        // S^T = K Q^T
        f32x16 sA = {}, sB = {};
        __builtin_amdgcn_s_setprio(1);
        #pragma unroll
        for (int ck = 0; ck < 4; ck++) {
            bf16x8 kf0 = *(const bf16x8*)(ldsK + j31 * 64        + (((2*ck + hi) ^ sw) * 8));
            bf16x8 kf1 = *(const bf16x8*)(ldsK + (32 + j31) * 64 + (((2*ck + hi) ^ sw) * 8));
            sA = mfma32(kf0, qf[ck], sA);
            sB = mfma32(kf1, qf[ck], sB);
        }
        __builtin_amdgcn_s_setprio(0);

        if ((fmask >> J) & 1ULL) {   // rare mask slow path
            const unsigned char* mp = mask + ((size_t)b * 2048 + q0 + j31) * 2048
                                           + (size_t)J * 64 + hi * 4;
            #pragma unroll
            for (int a2 = 0; a2 < 2; a2++)
                #pragma unroll
                for (int rg = 0; rg < 4; rg++) {
                    unsigned mb = *(const unsigned*)(mp + a2 * 32 + rg * 8);
                    #pragma unroll
                    for (int e = 0; e < 4; e++) {
                        if ((mb >> (8 * e)) & 0xFFu) {
                            if (a2 == 0) sA[rg * 4 + e] = -1e30f;
                            else         sB[rg * 4 + e] = -1e30f;
                        }
                    }
                }
        }

        // online softmax: max3 tree + raw v_exp
        float tm = fmaxf(sA[0], sA[1]);
        #pragma unroll
        for (int r = 2; r < 16; r += 2) tm = fmaxf(fmaxf(tm, sA[r]), sA[r + 1]);
        #pragma unroll
        for (int r = 0; r < 16; r += 2) tm = fmaxf(fmaxf(tm, sB[r]), sB[r + 1]);
        tm = fmaxf(tm, __shfl_xor(tm, 32));
        if (!__all(tm <= m + 8.f)) {        // defer-max (T13), log2 domain
            const float mnew = fmaxf(m, tm);
            const float fs = fexp2(m - mnew);
            m = mnew; l *= fs;
            #pragma unroll
            for (int r = 0; r < 16; r++) { oA[r] *= fs; oB[r] *= fs; }
        }
        float ps = 0.f;
        #pragma unroll
        for (int r = 0; r < 16; r++) { sA[r] = fexp2(sA[r] - m); ps += sA[r]; }
        #pragma unroll
        for (int r = 0; r < 16; r++) { sB[r] = fexp2(sB[r] - m); ps += sB[r]; }
        ps += __shfl_xor(ps, 32);
        l += ps;

        // P -> PV B-fragments: 16 cvt_pk + 8 permlane32_swap (T12)
        bf16x8 pb[4];
        #pragma unroll
        for (int c = 0; c < 4; c++) {
            const int rb = 8 * (c & 1);
            unsigned A0, B0, A1, B1;
            if (c < 2) {
                A0 = cvtpk(sA[rb],     sA[rb + 1]); B0 = cvtpk(sA[rb + 4], sA[rb + 5]);
                A1 = cvtpk(sA[rb + 2], sA[rb + 3]); B1 = cvtpk(sA[rb + 6], sA[rb + 7]);
            } else {
                A0 = cvtpk(sB[rb],     sB[rb + 1]); B0 = cvtpk(sB[rb + 4], sB[rb + 5]);
                A1 = cvtpk(sB[rb + 2], sB[rb + 3]); B1 = cvtpk(sB[rb + 6], sB[rb + 7]);
            }
            pl32swap(A0, B0); pl32swap(A1, B1);
            union { unsigned u[4]; bf16x8 v; } pu;
            pu.u[0] = A0; pu.u[1] = A1; pu.u[2] = B0; pu.u[3] = B1;
            pb[c] = pu.v;
        }

        // O^T += V^T P^T
        __builtin_amdgcn_s_setprio(1);
        #pragma unroll
        for (int c = 0; c < 4; c++) {
            bf16x8 vf0 = *(const bf16x8*)(ldsV + j31 * 64        + (((2*c + hi) ^ sw) * 8));
            bf16x8 vf1 = *(const bf16x8*)(ldsV + (32 + j31) * 64 + (((2*c + hi) ^ sw) * 8));
            oA = mfma32(vf0, pb[c], oA);
            oB = mfma32(vf1, pb[c], oB);
        }
        __builtin_amdgcn_s_setprio(0);
        __builtin_amdgcn_s_barrier();
    };

    #pragma unroll 1
    for (int jj = 0; jj < 16; ++jj) { tile(2 * jj, 0); tile(2 * jj + 1, 1); }

    // epilogue: transpose O^T -> O rows via LDS (stride 34 u32)
    __syncthreads();
    unsigned* ow = (unsigned*)&lds[0][0][0] + wave * (32 * 34);
    const float inv = 1.f / l;
    #pragma unroll
    for (int o = 0; o < 2; o++)
        #pragma unroll
        for (int rp = 0; rp < 8; rp++) {
            const int r  = 2 * rp;
            const int hd = 2 * (rp & 1) + 8 * (rp >> 1) + 4 * hi + 32 * o;
            const float v0 = (o ? oB[r]     : oA[r])     * inv;
            const float v1 = (o ? oB[r + 1] : oA[r + 1]) * inv;
            ow[j31 * 34 + (hd >> 1)] = cvtpk(v0, v1);
        }
    __syncthreads();
    {
        const size_t orow = ((size_t)b * 2048 + q0 + j31) * 1024 + h * 64 + hi * 32;
        unsigned* gout = (unsigned*)(O + orow);
        const unsigned* src = ow + j31 * 34 + hi * 16;
        #pragma unroll
        for (int i = 0; i < 4; i++) {
            u32x4v v;
            v[0] = src[i*4]; v[1] = src[i*4+1]; v[2] = src[i*4+2]; v[3] = src[i*4+3];
            *(u32x4v*)(gout + i * 4) = v;
        }
    }
}

// ---------------- launch ----------------------------------------------------
extern "C" void kernel_launch(void* const* d_in, const int* in_sizes, int n_in,
                              void* d_out, int out_size, void* d_ws, size_t ws_size,
                              hipStream_t stream)
{
    const float* query = (const float*)d_in[0];
    const float* key_  = (const float*)d_in[1];
    const float* value = (const float*)d_in[2];
    const unsigned char* amask = (const unsigned char*)d_in[3];
    const float* Wq = (const float*)d_in[4];
    const float* bq = (const float*)d_in[5];
    const float* Wk = (const float*)d_in[6];
    const float* bk = (const float*)d_in[7];
    const float* Wv = (const float*)d_in[8];
    const float* bv = (const float*)d_in[9];
    const float* Wo = (const float*)d_in[10];
    const float* bo = (const float*)d_in[11];
    float* out = (float*)d_out;

    char* ws = (char*)d_ws;
    const size_t MB = 1024 * 1024;
    short* Wqb = (short*)(ws + 0 * MB);    // 2 MB each
    short* Wkb = (short*)(ws + 2 * MB);
    short* Wvb = (short*)(ws + 4 * MB);
    short* Wob = (short*)(ws + 6 * MB);
    short* Qb  = (short*)(ws + 8 * MB);    // 16 MB each
    short* Kb  = (short*)(ws + 24 * MB);
    short* Vtb = (short*)(ws + 40 * MB);
    short* Xb  = (short*)(ws + 56 * MB);   // staging: Qin/Kin/Vin then attn-out
    unsigned char* flagsb = (unsigned char*)(ws + 0 * MB);  // Wqb region, dead post-Q-GEMM

    cvt_w4<<<2048, 256, 0, stream>>>(Wq, Wk, Wv, Wo, Wqb, Wkb, Wvb, Wob);

    const float qscale = 0.125f * 1.44269504088896f;   // 1/sqrt(64) * log2(e)
    cvt_one<<<4096, 256, 0, stream>>>(query, Xb);
    gemm_bt<0><<<512, 256, 0, stream>>>(Xb, Wqb, bq, Qb, qscale);
    cvt_one<<<4096, 256, 0, stream>>>(key_, Xb);
    gemm_bt<0><<<512, 256, 0, stream>>>(Xb, Wkb, bk, Kb, 1.0f);
    cvt_one<<<4096, 256, 0, stream>>>(value, Xb);
    gemm_bt<2><<<512, 256, 0, stream>>>(Xb, Wvb, bv, Vtb, 1.0f);

    mask_scan<<<256, 256, 0, stream>>>(amask, flagsb);

    attn_fwd2<<<1024, 256, 0, stream>>>(Qb, Kb, Vtb, amask, flagsb, Xb);

    gemm_bt<3><<<512, 256, 0, stream>>>(Xb, Wob, bo, out, 1.0f);
}